// Round 2
// baseline (155.788 us; speedup 1.0000x reference)
//
#include <hip/hip_runtime.h>
#include <hip/hip_bf16.h>
#include <math.h>

#define N_BATCH 256
#define C_CH    2048
#define HW      49
#define SIZE7   7
#define BLOCK   1024
#define WAVES   16                 // 1024/64
#define C_PER_W (C_CH / WAVES)     // 128 channels per wave

// One block per batch element n (256 blocks = 1 per CU, 16 waves each).
// Lane p (<49) accumulates over this wave's 128 channels:
//   q0: sum x          q1: sum x*W1[0]   q2: sum x*W1[1]
//   q3: sum x*W2[0]    q4: sum x*W2[1]
// Block-reduce 16 waves in LDS, then wave 0 runs the argmax + polar epilogue.
__global__ __launch_bounds__(BLOCK) void rpp_fused_kernel(
    const float* __restrict__ x, const float* __restrict__ Wlin,
    const float* __restrict__ b, float* __restrict__ out) {
  const int n    = blockIdx.x;
  const int tid  = threadIdx.x;
  const int lane = tid & 63;
  const int wave = tid >> 6;

  __shared__ __align__(16) float wlin_s[2 * 2 * C_CH];  // full Wlin, 32 KB
  __shared__ float red[WAVES][5][64];                   // 20 KB

  // Stage Wlin (8192 floats) into LDS with float4 loads: 2 per thread.
  {
    const float4* src = (const float4*)Wlin;
    float4* dst = (float4*)wlin_s;
#pragma unroll
    for (int i = tid; i < 2 * C_CH; i += BLOCK) dst[i] = src[i];
  }
  __syncthreads();

  // Weight slices in LDS:  W1[o,c]=wlin_s[o*4096+c], W2[o,c]=wlin_s[o*4096+2048+c]
  const float* w1r0 = wlin_s;                 // W1 row 0
  const float* w1r1 = wlin_s + 4096;          // W1 row 1
  const float* w2r0 = wlin_s + 2048;          // W2 row 0
  const float* w2r1 = wlin_s + 6144;          // W2 row 1

  // Lane p reads x[n, c, p]; lanes >= 49 clamp to p=0 (same cache line).
  const int lp = (lane < HW) ? lane : 0;
  const int cbase = wave * C_PER_W;
  const float* xp = x + (size_t)n * C_CH * HW + (size_t)cbase * HW + lp;

  float a0 = 0.f, a1 = 0.f, a2 = 0.f, a3 = 0.f, a4 = 0.f;
#pragma unroll 4
  for (int c = 0; c < C_PER_W; c += 4, xp += 4 * HW) {
    const float v0 = xp[0 * HW];
    const float v1 = xp[1 * HW];
    const float v2 = xp[2 * HW];
    const float v3 = xp[3 * HW];
    const float4 w0 = *(const float4*)&w1r0[cbase + c];
    const float4 w1 = *(const float4*)&w1r1[cbase + c];
    const float4 w2 = *(const float4*)&w2r0[cbase + c];
    const float4 w3 = *(const float4*)&w2r1[cbase + c];
    a0 += (v0 + v1) + (v2 + v3);
    a1 = fmaf(v0, w0.x, fmaf(v1, w0.y, fmaf(v2, w0.z, fmaf(v3, w0.w, a1))));
    a2 = fmaf(v0, w1.x, fmaf(v1, w1.y, fmaf(v2, w1.z, fmaf(v3, w1.w, a2))));
    a3 = fmaf(v0, w2.x, fmaf(v1, w2.y, fmaf(v2, w2.z, fmaf(v3, w2.w, a3))));
    a4 = fmaf(v0, w3.x, fmaf(v1, w3.y, fmaf(v2, w3.z, fmaf(v3, w3.w, a4))));
  }

  red[wave][0][lane] = a0;
  red[wave][1][lane] = a1;
  red[wave][2][lane] = a2;
  red[wave][3][lane] = a3;
  red[wave][4][lane] = a4;
  __syncthreads();

  if (wave != 0) return;

  // Reduce 16 waves (lane-local over LDS, conflict-free: consecutive lanes ->
  // consecutive addresses).
  float s0 = 0.f, s1 = 0.f, s2 = 0.f, s3 = 0.f, s4 = 0.f;
#pragma unroll
  for (int w = 0; w < WAVES; w++) {
    s0 += red[w][0][lane];
    s1 += red[w][1][lane];
    s2 += red[w][2][lane];
    s3 += red[w][3][lane];
    s4 += red[w][4][lane];
  }

  // argmax over p<49 of channel-sum (same order as the mean); first-max tie-break.
  float v = (lane < HW) ? s0 : -INFINITY;
  int vi = lane;
#pragma unroll
  for (int off = 32; off; off >>= 1) {
    const float ov = __shfl_down(v, off);
    const int oi = __shfl_down(vi, off);
    if (ov > v || (ov == v && oi < vi)) { v = ov; vi = oi; }
  }
  const int idx = __shfl(vi, 0);

  // anchor dot products: (max_feat @ W1^T)[n, o]
  const float anc0 = __shfl(s1, idx);
  const float anc1 = __shfl(s2, idx);
  const float b0 = b[0], b1 = b[1];

  float pred0 = fmaxf(s3 + anc0 + b0, 0.f);
  float pred1 = fmaxf(s4 + anc1 + b1, 0.f);
  if (lane == idx) { pred0 = 0.f; pred1 = 0.f; }

  const int li = lane / SIZE7, lj = lane % SIZE7;
  const int ai = idx / SIZE7, aj = idx % SIZE7;
  const float ri = (float)(li - ai) * (1.0f / SIZE7);
  const float rj = (float)(lj - aj) * (1.0f / SIZE7);
  const float rdist = sqrtf(ri * ri + rj * rj);
  // (atan2/pi + 1)/2 ; atan2f(0,0)=0 matches jnp at the anchor.
  const float rangle = atan2f(rj, ri) * 0.15915494309189535f + 0.5f;

  float dl = pred0 - rdist;
  dl *= dl;
  float gap = pred1 - rangle;
  if (gap < 0.f) gap += 1.f;

  // mean of gap over the 49 valid positions
  float g = (lane < HW) ? gap : 0.f;
#pragma unroll
  for (int off = 32; off; off >>= 1) g += __shfl_down(g, off);
  const float mean = __shfl(g, 0) * (1.0f / HW);
  gap -= mean;

  if (lane < HW) out[(size_t)n * HW + lane] = dl + gap * gap;
}

extern "C" void kernel_launch(void* const* d_in, const int* in_sizes, int n_in,
                              void* d_out, int out_size, void* d_ws, size_t ws_size,
                              hipStream_t stream) {
  const float* x    = (const float*)d_in[0];
  const float* Wlin = (const float*)d_in[1];
  const float* b    = (const float*)d_in[2];
  float* out = (float*)d_out;
  (void)d_ws; (void)ws_size;

  hipLaunchKernelGGL(rpp_fused_kernel, dim3(N_BATCH), dim3(BLOCK), 0,
                     stream, x, Wlin, b, out);
}

// Round 3
// 155.030 us; speedup vs baseline: 1.0049x; 1.0049x over previous
//
#include <hip/hip_runtime.h>
#include <hip/hip_bf16.h>
#include <math.h>

#define N_BATCH 256
#define C_CH    2048
#define HW      49
#define SIZE7   7
#define BLOCK   1024
#define WAVES   16
#define GRP_PER_W 32   // 4-channel groups per wave (= 128 channels per wave)

// One block per n. A "group" = 4 consecutive channels = 196 contiguous floats
// = 49 float4s, 16B-aligned (196*4 = 784 = 49*16). Lane l<49 loads float4 #l
// of the group: 784 contiguous bytes per wave instruction, no overfetch.
// Element m of lane l is flat e = 4l+m in the group -> channel offset
// cm = e/49, spatial p = e%49 -- both lane-constant across the whole loop
// (group stride 196 = 4*49 preserves the mapping). 5 sums per (p):
//   q0: sum x      q1..q4: sum x * {W1r0, W1r1, W2r0, W2r1}[c]
__global__ __launch_bounds__(BLOCK) void rpp_fused2_kernel(
    const float* __restrict__ x, const float* __restrict__ Wlin,
    const float* __restrict__ b, float* __restrict__ out) {
  const int n    = blockIdx.x;
  const int tid  = threadIdx.x;
  const int lane = tid & 63;
  const int wave = tid >> 6;

  __shared__ __align__(16) float w_s[4][C_CH];          // 32 KB: W1r0,W1r1,W2r0,W2r1
  __shared__ __align__(16) float red2[WAVES][5][64][4]; // 80 KB
  __shared__ float sfin[5][HW];

  // Stage weights as float4s. w_s row q <- Wlin rows in order W1r0,W1r1,W2r0,W2r1:
  // float4 offset = (q&1)*1024 + (q>>1)*512.
  {
    const float4* src = (const float4*)Wlin;
    float4* dst = (float4*)w_s;
    for (int j = tid; j < 2048; j += BLOCK) {
      const int q = j >> 9, c4 = j & 511;
      dst[j] = src[(q & 1) * 1024 + (q >> 1) * 512 + c4];
    }
  }
  __syncthreads();

  const int l = (lane < HW) ? lane : 0;   // lanes 49..63 duplicate lane 0 (same line)
  int cm[4];
#pragma unroll
  for (int m = 0; m < 4; m++) {
    const int e = 4 * l + m;
    cm[m] = (e >= 49) + (e >= 98) + (e >= 147);   // channel offset within group
  }

  const float* xg = x + (size_t)n * (C_CH * HW)
                      + (size_t)wave * (GRP_PER_W * 196) + 4 * l;

  float acc[5][4];
#pragma unroll
  for (int q = 0; q < 5; q++)
#pragma unroll
    for (int m = 0; m < 4; m++) acc[q][m] = 0.f;

  int gg = wave * GRP_PER_W;
#pragma unroll 4
  for (int i = 0; i < GRP_PER_W; i++, gg++, xg += 196) {
    const float4 v = *(const float4*)xg;
    // wave-uniform weight quads for this group's 4 channels (LDS broadcast)
    const float4 u0 = *(const float4*)&w_s[0][4 * gg];
    const float4 u1 = *(const float4*)&w_s[1][4 * gg];
    const float4 u2 = *(const float4*)&w_s[2][4 * gg];
    const float4 u3 = *(const float4*)&w_s[3][4 * gg];
    const float xv[4] = {v.x, v.y, v.z, v.w};
#pragma unroll
    for (int m = 0; m < 4; m++) {
      const int c = cm[m];   // lane-constant -> cndmask selects, hoistable masks
      const float w0 = (c == 0) ? u0.x : (c == 1) ? u0.y : (c == 2) ? u0.z : u0.w;
      const float w1 = (c == 0) ? u1.x : (c == 1) ? u1.y : (c == 2) ? u1.z : u1.w;
      const float w2 = (c == 0) ? u2.x : (c == 1) ? u2.y : (c == 2) ? u2.z : u2.w;
      const float w3 = (c == 0) ? u3.x : (c == 1) ? u3.y : (c == 2) ? u3.z : u3.w;
      acc[0][m] += xv[m];
      acc[1][m] = fmaf(xv[m], w0, acc[1][m]);
      acc[2][m] = fmaf(xv[m], w1, acc[2][m]);
      acc[3][m] = fmaf(xv[m], w2, acc[3][m]);
      acc[4][m] = fmaf(xv[m], w3, acc[4][m]);
    }
  }

#pragma unroll
  for (int q = 0; q < 5; q++) {
    const float4 t = make_float4(acc[q][0], acc[q][1], acc[q][2], acc[q][3]);
    *(float4*)&red2[wave][q][lane][0] = t;   // b128, conflict-free
  }
  __syncthreads();

  // Scatter-reduce (wave, l, m) -> (q, p): for p, contributors are e = p+49k,
  // k=0..3, at l=e>>2, m=e&3. Consecutive p -> consecutive LDS addrs.
  if (tid < 5 * HW) {
    const int q = tid / HW, p = tid % HW;
    float s = 0.f;
#pragma unroll
    for (int w = 0; w < WAVES; w++)
#pragma unroll
      for (int k = 0; k < 4; k++) {
        const int e = p + 49 * k;
        s += red2[w][q][e >> 2][e & 3];
      }
    sfin[q][p] = s;
  }
  __syncthreads();

  if (wave != 0) return;

  const int pl = (lane < HW) ? lane : 0;
  const float s0 = sfin[0][pl], s1 = sfin[1][pl], s2 = sfin[2][pl];
  const float s3 = sfin[3][pl], s4 = sfin[4][pl];

  // argmax over p<49 of channel-sum; first-max tie-break (matches jnp.argmax).
  float v = (lane < HW) ? s0 : -INFINITY;
  int vi = lane;
#pragma unroll
  for (int off = 32; off; off >>= 1) {
    const float ov = __shfl_down(v, off);
    const int oi = __shfl_down(vi, off);
    if (ov > v || (ov == v && oi < vi)) { v = ov; vi = oi; }
  }
  const int idx = __shfl(vi, 0);

  const float anc0 = __shfl(s1, idx);   // (max_feat @ W1^T)[n, 0]
  const float anc1 = __shfl(s2, idx);
  const float b0 = b[0], b1 = b[1];

  float pred0 = fmaxf(s3 + anc0 + b0, 0.f);
  float pred1 = fmaxf(s4 + anc1 + b1, 0.f);
  if (lane == idx) { pred0 = 0.f; pred1 = 0.f; }

  const int li = lane / SIZE7, lj = lane % SIZE7;
  const int ai = idx / SIZE7, aj = idx % SIZE7;
  const float ri = (float)(li - ai) * (1.0f / SIZE7);
  const float rj = (float)(lj - aj) * (1.0f / SIZE7);
  const float rdist = sqrtf(ri * ri + rj * rj);
  const float rangle = atan2f(rj, ri) * 0.15915494309189535f + 0.5f;

  float dl = pred0 - rdist;
  dl *= dl;
  float gap = pred1 - rangle;
  if (gap < 0.f) gap += 1.f;

  float g = (lane < HW) ? gap : 0.f;
#pragma unroll
  for (int off = 32; off; off >>= 1) g += __shfl_down(g, off);
  const float mean = __shfl(g, 0) * (1.0f / HW);
  gap -= mean;

  if (lane < HW) out[(size_t)n * HW + lane] = dl + gap * gap;
}

extern "C" void kernel_launch(void* const* d_in, const int* in_sizes, int n_in,
                              void* d_out, int out_size, void* d_ws, size_t ws_size,
                              hipStream_t stream) {
  const float* x    = (const float*)d_in[0];
  const float* Wlin = (const float*)d_in[1];
  const float* b    = (const float*)d_in[2];
  float* out = (float*)d_out;
  (void)d_ws; (void)ws_size;

  hipLaunchKernelGGL(rpp_fused2_kernel, dim3(N_BATCH), dim3(BLOCK), 0,
                     stream, x, Wlin, b, out);
}